// Round 9
// baseline (100.080 us; speedup 1.0000x reference)
//
#include <hip/hip_runtime.h>
#include <math.h>

// BoundaryLoss — B=32, C=1, H=W=512 fp32. loss = mean(bce(sigmoid(pred),t) * (1+4*boundary)),
// boundary = (boxsum5(t)>0) - (boxsum5(t)==25), zero padding.
//
// R9 = R8 bl_main (branch-free loads, RPW=2, WPB=8, 1024 blocks) with the
// finalize kernel ELIMINATED: per-block atomicAdd(out, partial*INV_N), out
// zeroed by a 4-byte hipMemsetAsync node (cheapest possible graph node).
// Unlike R4/R5's fused spin (regressed), this is fire-and-forget — no polling.
// Float atomic order-nondeterminism ~1e-6 << 0.08 threshold.
//  - R2/R6/R7/R8 tie at 97.5-98.3 across occupancy/ILP/traffic variants:
//    bl_main is pinned by cold-HBM fetch (ws-poison evicts L3); last
//    controllable term is the second kernel node's launch overhead.
//  - lane owns 8 cols (64 lanes = W=512); target packed 1 byte/col in u64;
//    horiz 5-tap = byte-shifted adds w/ __shfl halo; vert 5-tap over 6 rows;
//  - bce = min(softplus((1-2t)x),100) via __expf/__logf (err ~1e-5 << thr 0.08).

typedef unsigned long long u64;
typedef float v4f __attribute__((ext_vector_type(4)));

constexpr int NB = 32, H = 512, W = 512;
constexpr int RPW = 2;                   // output rows per wave
constexpr int SPI = H / RPW;             // 256 strips per image
constexpr int WPB = 8;                   // waves per block (512 threads)
constexpr int NBLK = NB * SPI / WPB;     // 1024 blocks
constexpr float INV_N = 1.0f / (float)(NB * H * W);

__device__ __forceinline__ u64 pack8(v4f a, v4f b) {
    // t in {0.0f,1.0f}: bit23 of the fp32 pattern -> 1 byte per column.
    unsigned a0 = __builtin_bit_cast(unsigned, a.x), a1 = __builtin_bit_cast(unsigned, a.y),
             a2 = __builtin_bit_cast(unsigned, a.z), a3 = __builtin_bit_cast(unsigned, a.w);
    unsigned b0 = __builtin_bit_cast(unsigned, b.x), b1 = __builtin_bit_cast(unsigned, b.y),
             b2 = __builtin_bit_cast(unsigned, b.z), b3 = __builtin_bit_cast(unsigned, b.w);
    unsigned lo = ((a0 >> 23) & 0x1u)      | ((a1 >> 15) & 0x100u)
                | ((a2 >> 7)  & 0x10000u)  | ((a3 << 1)  & 0x1000000u);
    unsigned hi = ((b0 >> 23) & 0x1u)      | ((b1 >> 15) & 0x100u)
                | ((b2 >> 7)  & 0x10000u)  | ((b3 << 1)  & 0x1000000u);
    return (u64)lo | ((u64)hi << 32);
}

__device__ __forceinline__ float bce_one(float x, unsigned tbit, unsigned s) {
    float y = tbit ? -x : x;                       // t==1 -> softplus(-x); t==0 -> softplus(x)
    float sp = fmaxf(y, 0.0f) + __logf(1.0f + __expf(-fabsf(y)));
    float w = (s - 1u) < 24u ? 5.0f : 1.0f;        // s==0 or s==25 -> 1, else 5
    return w * fminf(sp, 100.0f);
}

__global__ __launch_bounds__(512, 4) void bl_main(
    const float* __restrict__ pred, const float* __restrict__ tgt,
    float* __restrict__ out)
{
    const int tid  = threadIdx.x;
    const int lane = tid & 63;
    const int widx = tid >> 6;
    const int blk  = blockIdx.x;
    const int g    = blk * WPB + widx;              // global wave id, 0..8191
    const int b    = g >> 8;                        // g / SPI (SPI==256)
    const int r0   = (g & (SPI - 1)) * RPW;         // first output row
    const int c    = lane * 8;
    const float* tb = tgt  + (size_t)b * H * W + c;
    const float* pb = pred + (size_t)b * H * W + c;

    // ---- all loads branch-free, issued up front (single latency ramp) ----
    v4f traw[6][2];                                 // 6 clamped target rows
#pragma unroll
    for (int i = 0; i < 6; ++i) {
        int r = r0 - 2 + i;
        int rc = r < 0 ? 0 : (r > H - 1 ? H - 1 : r);   // clamp: load always
        const v4f* tp = (const v4f*)(tb + (size_t)rc * W);
        traw[i][0] = tp[0];
        traw[i][1] = tp[1];
    }
    const v4f* pr0 = (const v4f*)(pb + (size_t)r0 * W);
    const v4f* pr1 = (const v4f*)(pb + (size_t)(r0 + 1) * W);
    v4f p00 = pr0[0], p01 = pr0[1];
    v4f p10 = pr1[0], p11 = pr1[1];

    // ---- pack + zero out-of-range rows (select, no branch) ----
    u64 vrow[6], hrow[6];
#pragma unroll
    for (int i = 0; i < 6; ++i) {
        int r = r0 - 2 + i;
        u64 v = pack8(traw[i][0], traw[i][1]);
        v = ((unsigned)r < (unsigned)H) ? v : 0ull; // wave-uniform select
        u64 lv = __shfl_up(v, 1, 64);
        u64 rv = __shfl_down(v, 1, 64);
        if (lane == 0)  lv = 0;                     // zero pad at image edges
        if (lane == 63) rv = 0;
        // horizontal 5-tap, byte-wise (max 5 per byte: no carry)
        hrow[i] = v + ((v << 8) | (lv >> 56)) + ((v << 16) | (lv >> 48))
                    + ((v >> 8) | (rv << 56)) + ((v >> 16) | (rv << 48));
        vrow[i] = v;
    }

    float acc = 0.0f;
#pragma unroll
    for (int j = 0; j < RPW; ++j) {                 // output rows r0+j
        u64 S  = hrow[j] + hrow[j+1] + hrow[j+2] + hrow[j+3] + hrow[j+4]; // bytes <= 25
        u64 vc = vrow[j + 2];                       // center target row
        v4f p0 = (j == 0) ? p00 : p10;
        v4f p1 = (j == 0) ? p01 : p11;
        unsigned vl = (unsigned)vc,         Sl = (unsigned)S;
        unsigned vh = (unsigned)(vc >> 32), Sh = (unsigned)(S >> 32);
        acc += bce_one(p0.x,  vl        & 1u,  Sl        & 0xFFu);
        acc += bce_one(p0.y, (vl >>  8) & 1u, (Sl >>  8) & 0xFFu);
        acc += bce_one(p0.z, (vl >> 16) & 1u, (Sl >> 16) & 0xFFu);
        acc += bce_one(p0.w, (vl >> 24) & 1u, (Sl >> 24) & 0xFFu);
        acc += bce_one(p1.x,  vh        & 1u,  Sh        & 0xFFu);
        acc += bce_one(p1.y, (vh >>  8) & 1u, (Sh >>  8) & 0xFFu);
        acc += bce_one(p1.z, (vh >> 16) & 1u, (Sh >> 16) & 0xFFu);
        acc += bce_one(p1.w, (vh >> 24) & 1u, (Sh >> 24) & 0xFFu);
    }

    // wave reduce, then one LDS hop (the only barrier)
    #pragma unroll
    for (int off = 32; off > 0; off >>= 1)
        acc += __shfl_down(acc, off, 64);
    __shared__ float wsum[WPB];
    if (lane == 0) wsum[widx] = acc;
    __syncthreads();
    if (tid == 0) {
        float s = 0.0f;
        #pragma unroll
        for (int k = 0; k < WPB; ++k) s += wsum[k];
        // fire-and-forget device-scope atomic: no second kernel node.
        atomicAdd(out, s * INV_N);
    }
}

extern "C" void kernel_launch(void* const* d_in, const int* in_sizes, int n_in,
                              void* d_out, int out_size, void* d_ws, size_t ws_size,
                              hipStream_t stream) {
    const float* pred = (const float*)d_in[0];
    const float* tgt  = (const float*)d_in[1];
    float* out = (float*)d_out;

    hipMemsetAsync(out, 0, sizeof(float), stream);   // out is poisoned 0xAA
    bl_main<<<NBLK, 512, 0, stream>>>(pred, tgt, out);
}

// Round 10
// 95.780 us; speedup vs baseline: 1.0449x; 1.0449x over previous
//
#include <hip/hip_runtime.h>
#include <math.h>

// BoundaryLoss — B=32, C=1, H=W=512 fp32. loss = mean(bce(sigmoid(pred),t) * (1+4*boundary)),
// boundary = (boxsum5(t)>0) - (boxsum5(t)==25), zero padding.
//
// R10 = exact revert to R8 (measured best: 97.5 us; R9's memset+atomic
// finalize regressed to 100.1).
// Final structure & why (session evidence):
//  - RPW=2, WPB=8, 1024 blocks, branch-free clamped loads issued up front:
//    one cold-HBM latency ramp. R2/R6/R7/R8 tie (97.5-98.3) across occupancy
//    16-32 waves/CU, RPW 2/4, WPB 4/8 -> bl_main pinned by cold fetch of the
//    67 MB inputs (the harness's 268 MB ws-poison evicts L3 every iteration).
//  - separate tiny finalize kernel beats fused-spin (R4/R5: +6..+13 us) and
//    memset+atomicAdd (R9: +2.6 us).
//  - no XCD swizzle, no non-temporal loads (R3: both regress).
//  - lane owns 8 cols (64 lanes = W=512); target packed 1 byte/col in u64;
//    horiz 5-tap = byte-shifted adds w/ __shfl halo; vert 5-tap over 6 rows.
//  - bce = min(softplus((1-2t)x),100) via __expf/__logf (err ~1e-5 << thr 0.08).
// Cost floor: ~73 us fixed harness reset traffic (268 MB poison + 134 MB
// restores at ~80% HBM peak) + ~25 us kernel-side (>=10.6 us cold 67 MB read).

typedef unsigned long long u64;
typedef float v4f __attribute__((ext_vector_type(4)));

constexpr int NB = 32, H = 512, W = 512;
constexpr int RPW = 2;                   // output rows per wave
constexpr int SPI = H / RPW;             // 256 strips per image
constexpr int WPB = 8;                   // waves per block (512 threads)
constexpr int NBLK = NB * SPI / WPB;     // 1024 blocks
constexpr float INV_N = 1.0f / (float)(NB * H * W);

__device__ __forceinline__ u64 pack8(v4f a, v4f b) {
    // t in {0.0f,1.0f}: bit23 of the fp32 pattern -> 1 byte per column.
    unsigned a0 = __builtin_bit_cast(unsigned, a.x), a1 = __builtin_bit_cast(unsigned, a.y),
             a2 = __builtin_bit_cast(unsigned, a.z), a3 = __builtin_bit_cast(unsigned, a.w);
    unsigned b0 = __builtin_bit_cast(unsigned, b.x), b1 = __builtin_bit_cast(unsigned, b.y),
             b2 = __builtin_bit_cast(unsigned, b.z), b3 = __builtin_bit_cast(unsigned, b.w);
    unsigned lo = ((a0 >> 23) & 0x1u)      | ((a1 >> 15) & 0x100u)
                | ((a2 >> 7)  & 0x10000u)  | ((a3 << 1)  & 0x1000000u);
    unsigned hi = ((b0 >> 23) & 0x1u)      | ((b1 >> 15) & 0x100u)
                | ((b2 >> 7)  & 0x10000u)  | ((b3 << 1)  & 0x1000000u);
    return (u64)lo | ((u64)hi << 32);
}

__device__ __forceinline__ float bce_one(float x, unsigned tbit, unsigned s) {
    float y = tbit ? -x : x;                       // t==1 -> softplus(-x); t==0 -> softplus(x)
    float sp = fmaxf(y, 0.0f) + __logf(1.0f + __expf(-fabsf(y)));
    float w = (s - 1u) < 24u ? 5.0f : 1.0f;        // s==0 or s==25 -> 1, else 5
    return w * fminf(sp, 100.0f);
}

__global__ __launch_bounds__(512, 4) void bl_main(
    const float* __restrict__ pred, const float* __restrict__ tgt,
    float* __restrict__ partials)
{
    const int tid  = threadIdx.x;
    const int lane = tid & 63;
    const int widx = tid >> 6;
    const int blk  = blockIdx.x;
    const int g    = blk * WPB + widx;              // global wave id, 0..8191
    const int b    = g >> 8;                        // g / SPI (SPI==256)
    const int r0   = (g & (SPI - 1)) * RPW;         // first output row
    const int c    = lane * 8;
    const float* tb = tgt  + (size_t)b * H * W + c;
    const float* pb = pred + (size_t)b * H * W + c;

    // ---- all loads branch-free, issued up front (single latency ramp) ----
    v4f traw[6][2];                                 // 6 clamped target rows
#pragma unroll
    for (int i = 0; i < 6; ++i) {
        int r = r0 - 2 + i;
        int rc = r < 0 ? 0 : (r > H - 1 ? H - 1 : r);   // clamp: load always
        const v4f* tp = (const v4f*)(tb + (size_t)rc * W);
        traw[i][0] = tp[0];
        traw[i][1] = tp[1];
    }
    const v4f* pr0 = (const v4f*)(pb + (size_t)r0 * W);
    const v4f* pr1 = (const v4f*)(pb + (size_t)(r0 + 1) * W);
    v4f p00 = pr0[0], p01 = pr0[1];
    v4f p10 = pr1[0], p11 = pr1[1];

    // ---- pack + zero out-of-range rows (select, no branch) ----
    u64 vrow[6], hrow[6];
#pragma unroll
    for (int i = 0; i < 6; ++i) {
        int r = r0 - 2 + i;
        u64 v = pack8(traw[i][0], traw[i][1]);
        v = ((unsigned)r < (unsigned)H) ? v : 0ull; // wave-uniform select
        u64 lv = __shfl_up(v, 1, 64);
        u64 rv = __shfl_down(v, 1, 64);
        if (lane == 0)  lv = 0;                     // zero pad at image edges
        if (lane == 63) rv = 0;
        // horizontal 5-tap, byte-wise (max 5 per byte: no carry)
        hrow[i] = v + ((v << 8) | (lv >> 56)) + ((v << 16) | (lv >> 48))
                    + ((v >> 8) | (rv << 56)) + ((v >> 16) | (rv << 48));
        vrow[i] = v;
    }

    float acc = 0.0f;
#pragma unroll
    for (int j = 0; j < RPW; ++j) {                 // output rows r0+j
        u64 S  = hrow[j] + hrow[j+1] + hrow[j+2] + hrow[j+3] + hrow[j+4]; // bytes <= 25
        u64 vc = vrow[j + 2];                       // center target row
        v4f p0 = (j == 0) ? p00 : p10;
        v4f p1 = (j == 0) ? p01 : p11;
        unsigned vl = (unsigned)vc,         Sl = (unsigned)S;
        unsigned vh = (unsigned)(vc >> 32), Sh = (unsigned)(S >> 32);
        acc += bce_one(p0.x,  vl        & 1u,  Sl        & 0xFFu);
        acc += bce_one(p0.y, (vl >>  8) & 1u, (Sl >>  8) & 0xFFu);
        acc += bce_one(p0.z, (vl >> 16) & 1u, (Sl >> 16) & 0xFFu);
        acc += bce_one(p0.w, (vl >> 24) & 1u, (Sl >> 24) & 0xFFu);
        acc += bce_one(p1.x,  vh        & 1u,  Sh        & 0xFFu);
        acc += bce_one(p1.y, (vh >>  8) & 1u, (Sh >>  8) & 0xFFu);
        acc += bce_one(p1.z, (vh >> 16) & 1u, (Sh >> 16) & 0xFFu);
        acc += bce_one(p1.w, (vh >> 24) & 1u, (Sh >> 24) & 0xFFu);
    }

    // wave reduce, then one LDS hop (the only barrier)
    #pragma unroll
    for (int off = 32; off > 0; off >>= 1)
        acc += __shfl_down(acc, off, 64);
    __shared__ float wsum[WPB];
    if (lane == 0) wsum[widx] = acc;
    __syncthreads();
    if (tid == 0) {
        float s = 0.0f;
        #pragma unroll
        for (int k = 0; k < WPB; ++k) s += wsum[k];
        partials[blk] = s;
    }
}

__global__ __launch_bounds__(256) void bl_final(
    const float* __restrict__ p, float* __restrict__ out)
{
    const int tid = threadIdx.x;
    float v = 0.0f;
    #pragma unroll
    for (int k = 0; k < NBLK / 256; ++k)            // NBLK == 1024 -> 4 terms
        v += p[tid + k * 256];
    #pragma unroll
    for (int off = 32; off > 0; off >>= 1)
        v += __shfl_down(v, off, 64);
    __shared__ float wsum[4];
    if ((tid & 63) == 0) wsum[tid >> 6] = v;
    __syncthreads();
    if (tid == 0)
        out[0] = (wsum[0] + wsum[1] + wsum[2] + wsum[3]) * INV_N;
}

extern "C" void kernel_launch(void* const* d_in, const int* in_sizes, int n_in,
                              void* d_out, int out_size, void* d_ws, size_t ws_size,
                              hipStream_t stream) {
    const float* pred = (const float*)d_in[0];
    const float* tgt  = (const float*)d_in[1];
    float* partials = (float*)d_ws;                 // 1024 floats, fully overwritten
    float* out = (float*)d_out;

    bl_main<<<NBLK, 512, 0, stream>>>(pred, tgt, partials);
    bl_final<<<1, 256, 0, stream>>>(partials, out);
}